// Round 12
// baseline (144.560 us; speedup 1.0000x reference)
//
#include <hip/hip_runtime.h>
#include <math.h>

// Problem constants
#define M_ 16
#define N_ 4096
#define D_ 128
#define P_ 8192
#define H_ 32

// Projection tiling
#define NIC 32
#define ICH (N_/NIC)
#define NCB 16            // 256-column blocks, 1 col/thread

// Attention chunking
#define CHUNK 128
#define NCH (P_/CHUNK)    // 64 cache chunks
#define NCH1 (NCH+1)      // +1 for the 16 appended rows

// Workspace layout (float offsets)
#define QKV_SZ    (3*H_*M_*D_)
#define PART_OFF  (QKV_SZ)
#define OPART_OFF (QKV_SZ)
#define OPART_SZ  (H_*NCH1*M_*D_)
#define ML_OFF    (OPART_OFF + OPART_SZ)

// ---------------------------------------------------------------------------
// Kernel 1: partial QKV projection. grid (NCB, NIC, 3), block 256. (as r7)
// ---------------------------------------------------------------------------
__global__ __launch_bounds__(256) void k_proj(const float* __restrict__ X,
                                              const float* __restrict__ Wq,
                                              const float* __restrict__ Wk,
                                              const float* __restrict__ Wv,
                                              float* __restrict__ part) {
  const int mat = blockIdx.z;
  const float* __restrict__ W = (mat == 0) ? Wq : ((mat == 1) ? Wk : Wv);
  const int cb = blockIdx.x, ic = blockIdx.y;
  const int t = threadIdx.x;
  const int j0 = cb * 256 + t;
  const int i0 = ic * ICH;

  __shared__ __align__(16) float XT[ICH][20];

  {
    const int i_l = t & 127, mh = t >> 7;
#pragma unroll
    for (int r = 0; r < 8; ++r)
      XT[i_l][mh * 8 + r] = X[(size_t)(mh * 8 + r) * N_ + i0 + i_l];
  }
  __syncthreads();

  float acc[16];
#pragma unroll
  for (int m = 0; m < 16; ++m) acc[m] = 0.f;

#pragma unroll 8
  for (int i = 0; i < ICH; ++i) {
    const float wv = __builtin_nontemporal_load(W + (size_t)(i0 + i) * N_ + j0);
    float xr[16];
    {
      float4 xv;
      xv = *reinterpret_cast<const float4*>(&XT[i][0]);
      xr[0] = xv.x; xr[1] = xv.y; xr[2] = xv.z; xr[3] = xv.w;
      xv = *reinterpret_cast<const float4*>(&XT[i][4]);
      xr[4] = xv.x; xr[5] = xv.y; xr[6] = xv.z; xr[7] = xv.w;
      xv = *reinterpret_cast<const float4*>(&XT[i][8]);
      xr[8] = xv.x; xr[9] = xv.y; xr[10] = xv.z; xr[11] = xv.w;
      xv = *reinterpret_cast<const float4*>(&XT[i][12]);
      xr[12] = xv.x; xr[13] = xv.y; xr[14] = xv.z; xr[15] = xv.w;
    }
#pragma unroll
    for (int m = 0; m < 16; ++m) acc[m] = fmaf(xr[m], wv, acc[m]);
  }

#pragma unroll
  for (int m = 0; m < 16; ++m)
    __builtin_nontemporal_store(acc[m], part + (size_t)((mat * NIC + ic) * M_ + m) * N_ + j0);
}

// ---------------------------------------------------------------------------
// Kernel 2: reduce partials, RMS-norm q/k, relayout. (as r7)
// ---------------------------------------------------------------------------
__global__ __launch_bounds__(256) void k_reduce(const float* __restrict__ part,
                                                float* __restrict__ qkv) {
  const int mat = blockIdx.z, m = blockIdx.y, nc = blockIdx.x;
  const int t = threadIdx.x;
  const int n = nc * 256 + t;

  float s = 0.f;
#pragma unroll
  for (int ic = 0; ic < NIC; ++ic)
    s += __builtin_nontemporal_load(part + (size_t)((mat * NIC + ic) * M_ + m) * N_ + n);

  float ss = s * s;
#pragma unroll
  for (int off = 1; off < 64; off <<= 1) ss += __shfl_xor(ss, off);
  __shared__ float wsum[4];
  const int wave = t >> 6, lane = t & 63;
  if (lane == 0) wsum[wave] = ss;
  __syncthreads();
  const int half = t >> 7;
  const float tot = wsum[half * 2] + wsum[half * 2 + 1];
  const float scale = (mat < 2) ? rsqrtf(tot * (1.0f / 128.0f)) : 1.0f;

  const int h = n >> 7, d = n & 127;
  qkv[(size_t)((mat * H_ + h) * M_ + m) * D_ + d] = s * scale;
}

// ---------------------------------------------------------------------------
// fold8: reduce a[0..7] over the 8 dq-lanes (lane bits 0..2).
// Returns the fully-summed S[m_local=dq] on lane dq.
// ---------------------------------------------------------------------------
__device__ __forceinline__ float fold8(float a[8], int dq) {
#pragma unroll
  for (int i = 0; i < 4; ++i) {
    const float send = (dq & 4) ? a[i] : a[i + 4];
    const float recv = __shfl_xor(send, 4);
    a[i] = ((dq & 4) ? a[i + 4] : a[i]) + recv;
  }
#pragma unroll
  for (int i = 0; i < 2; ++i) {
    const float send = (dq & 2) ? a[i] : a[i + 2];
    const float recv = __shfl_xor(send, 2);
    a[i] = ((dq & 2) ? a[i + 2] : a[i]) + recv;
  }
  {
    const float send = (dq & 1) ? a[0] : a[1];
    const float recv = __shfl_xor(send, 1);
    a[0] = ((dq & 1) ? a[1] : a[0]) + recv;
  }
  return a[0];
}

// ---------------------------------------------------------------------------
// Kernel 3: p-split attention, LDS-lean + software-pipelined.
// grid (NCH1, H_), block 512 = 8 waves = 4 row-groups x 2 m-halves.
// Deltas vs r11 (same arithmetic, same merge — r11 passed at 0.0078):
//  (a) fused mi-loop: one qv read (4 x ds_read_b128) serves BOTH kA and kB
//      row-groups -> q LDS reads 128 -> 64 per chunk/wave. r11's per-CU LDS
//      throughput (~65 waves x 192 b128 x ~5-12cy on the shared LDS pipe)
//      was the hidden ~50+ us wall (conflict-free, so BANK_CONFLICT showed 0).
//  (b) cross-batch K prefetch: kk[8] is dead after the FMA loop; next batch's
//      K is loaded there immediately -> in flight across fold+softmax+PV
//      (~1200 cyc). vv issued BEFORE kk so PV's vmcnt wait (FIFO) does not
//      drain the kk prefetch.
// ---------------------------------------------------------------------------
__global__ __launch_bounds__(512, 2) void k_attn(const float* __restrict__ cacheK,
                                                 const float* __restrict__ cacheV,
                                                 const float* __restrict__ qkv,
                                                 float* __restrict__ opart,
                                                 float* __restrict__ ml) {
  const int c = blockIdx.x, h = blockIdx.y;
  const int t = threadIdx.x;
  const int wave = t >> 6, lane = t & 63;
  const int valid = (c < NCH) ? CHUNK : M_;
  const float* __restrict__ Ksrc = (c < NCH)
      ? (cacheK + ((size_t)h * P_ + (size_t)c * CHUNK) * D_)
      : (qkv + (size_t)((1 * H_ + h) * M_) * D_);
  const float* __restrict__ Vsrc = (c < NCH)
      ? (cacheV + ((size_t)h * P_ + (size_t)c * CHUNK) * D_)
      : (qkv + (size_t)((2 * H_ + h) * M_) * D_);

  __shared__ __align__(16) float smem[8192];     // 32 KB: qs[2048] + wx[1024] / obuf[8192]
  __shared__ __align__(16) float mlx[8][8][2];   // per-wave (m, l)

  float* qs = smem;                        // [16][128]
  float* wxp = smem + 2048 + wave * 128;   // wave-private [16 rows][8 m]

  // stage q (16x128)
  {
    const float4* src = reinterpret_cast<const float4*>(qkv + (size_t)(h * M_) * D_);
    reinterpret_cast<float4*>(qs)[t] = src[t];
  }
  __syncthreads();

  const int pg = lane >> 3, dq = lane & 7;
  const int dl = lane * 2;
  const int rg = wave >> 1, mbase = (wave & 1) * 8;
  const int rbase = rg * 32;
  int rc = valid - rbase; rc = (rc < 0) ? 0 : ((rc > 32) ? 32 : rc);
  const int nb = rc >> 4;   // 16-row batches: 2, 1, or 0

  float mrun = -3.0e38f, lrun = 0.f;
  float2 o[8];
#pragma unroll
  for (int mi = 0; mi < 8; ++mi) o[mi] = make_float2(0.f, 0.f);

  // K register block: kk[0..3] = row r0+pg (4 d-slices), kk[4..7] = row r0+8+pg
  float4 kk[8];
  if (nb > 0) {
    const float* ka = Ksrc + (size_t)(rbase + pg) * D_ + dq * 4;
    kk[0] = *reinterpret_cast<const float4*>(ka);
    kk[1] = *reinterpret_cast<const float4*>(ka + 32);
    kk[2] = *reinterpret_cast<const float4*>(ka + 64);
    kk[3] = *reinterpret_cast<const float4*>(ka + 96);
    const float* kb = Ksrc + (size_t)(rbase + 8 + pg) * D_ + dq * 4;
    kk[4] = *reinterpret_cast<const float4*>(kb);
    kk[5] = *reinterpret_cast<const float4*>(kb + 32);
    kk[6] = *reinterpret_cast<const float4*>(kb + 64);
    kk[7] = *reinterpret_cast<const float4*>(kb + 96);
  }

#pragma unroll 1
  for (int b = 0; b < nb; ++b) {
    const int r0 = rbase + b * 16;

    // ---- scores, fused over both row-groups: one qv read serves kA and kB --
    float aA[8], aB[8];
#pragma unroll
    for (int mi = 0; mi < 8; ++mi) {
      const float* qrow = qs + (mbase + mi) * D_ + dq * 4;
      const float4 q0 = *reinterpret_cast<const float4*>(qrow);
      const float4 q1 = *reinterpret_cast<const float4*>(qrow + 32);
      const float4 q2 = *reinterpret_cast<const float4*>(qrow + 64);
      const float4 q3 = *reinterpret_cast<const float4*>(qrow + 96);
      float sa, sb;
      sa = q0.x * kk[0].x;
      sa = fmaf(q0.y, kk[0].y, sa); sa = fmaf(q0.z, kk[0].z, sa); sa = fmaf(q0.w, kk[0].w, sa);
      sa = fmaf(q1.x, kk[1].x, sa); sa = fmaf(q1.y, kk[1].y, sa);
      sa = fmaf(q1.z, kk[1].z, sa); sa = fmaf(q1.w, kk[1].w, sa);
      sa = fmaf(q2.x, kk[2].x, sa); sa = fmaf(q2.y, kk[2].y, sa);
      sa = fmaf(q2.z, kk[2].z, sa); sa = fmaf(q2.w, kk[2].w, sa);
      sa = fmaf(q3.x, kk[3].x, sa); sa = fmaf(q3.y, kk[3].y, sa);
      sa = fmaf(q3.z, kk[3].z, sa); sa = fmaf(q3.w, kk[3].w, sa);
      sb = q0.x * kk[4].x;
      sb = fmaf(q0.y, kk[4].y, sb); sb = fmaf(q0.z, kk[4].z, sb); sb = fmaf(q0.w, kk[4].w, sb);
      sb = fmaf(q1.x, kk[5].x, sb); sb = fmaf(q1.y, kk[5].y, sb);
      sb = fmaf(q1.z, kk[5].z, sb); sb = fmaf(q1.w, kk[5].w, sb);
      sb = fmaf(q2.x, kk[6].x, sb); sb = fmaf(q2.y, kk[6].y, sb);
      sb = fmaf(q2.z, kk[6].z, sb); sb = fmaf(q2.w, kk[6].w, sb);
      sb = fmaf(q3.x, kk[7].x, sb); sb = fmaf(q3.y, kk[7].y, sb);
      sb = fmaf(q3.z, kk[7].z, sb); sb = fmaf(q3.w, kk[7].w, sb);
      aA[mi] = sa; aB[mi] = sb;
      __builtin_amdgcn_sched_barrier(0);  // cap qv ds_read clustering (r9 lesson)
    }

    // ---- V loads for this batch, issued FIRST (PV waits only on these) ----
    float2 vvA[8], vvB[8];
#pragma unroll
    for (int j = 0; j < 8; ++j)
      vvA[j] = *reinterpret_cast<const float2*>(Vsrc + (size_t)(r0 + j) * D_ + dl);
#pragma unroll
    for (int j = 0; j < 8; ++j)
      vvB[j] = *reinterpret_cast<const float2*>(Vsrc + (size_t)(r0 + 8 + j) * D_ + dl);

    // ---- cross-batch K prefetch into the now-dead kk registers ----
    {
      int rn = r0 + 16 + pg;
      rn = (rn < valid) ? rn : (valid - 1);   // phantom on last batch
      const float* ka = Ksrc + (size_t)rn * D_ + dq * 4;
      kk[0] = *reinterpret_cast<const float4*>(ka);
      kk[1] = *reinterpret_cast<const float4*>(ka + 32);
      kk[2] = *reinterpret_cast<const float4*>(ka + 64);
      kk[3] = *reinterpret_cast<const float4*>(ka + 96);
      int rn2 = r0 + 24 + pg;
      rn2 = (rn2 < valid) ? rn2 : (valid - 1);
      const float* kb = Ksrc + (size_t)rn2 * D_ + dq * 4;
      kk[4] = *reinterpret_cast<const float4*>(kb);
      kk[5] = *reinterpret_cast<const float4*>(kb + 32);
      kk[6] = *reinterpret_cast<const float4*>(kb + 64);
      kk[7] = *reinterpret_cast<const float4*>(kb + 96);
    }

    // ---- folds + online softmax over the 16 rows ----
    const float sA = fold8(aA, dq);
    const float sB = fold8(aB, dq);
    float tmax = fmaxf(sA, sB);
    tmax = fmaxf(tmax, __shfl_xor(tmax, 8));
    tmax = fmaxf(tmax, __shfl_xor(tmax, 16));
    tmax = fmaxf(tmax, __shfl_xor(tmax, 32));
    const float mnew = fmaxf(mrun, tmax);
    const float fc = __expf(mrun - mnew);
    mrun = mnew;
    const float wA = __expf(sA - mnew);
    const float wB = __expf(sB - mnew);
    float rs = wA + wB;
    rs += __shfl_xor(rs, 8); rs += __shfl_xor(rs, 16); rs += __shfl_xor(rs, 32);
    lrun = lrun * fc + rs;

    // publish weights (wave-private strip; same-wave RAW ordered by lgkmcnt)
    wxp[pg * 8 + dq] = wA;
    wxp[(8 + pg) * 8 + dq] = wB;

    // ---- rescale o by this batch's factor (per-m fc gathered via shfl) ----
#pragma unroll
    for (int mi = 0; mi < 8; ++mi) {
      const float fcm = __shfl(fc, (lane & 56) | mi);
      o[mi].x *= fcm; o[mi].y *= fcm;
    }

    // ---- PV rows r0..r0+7 ----
#pragma unroll
    for (int j = 0; j < 8; ++j) {
      const float4 w0 = *reinterpret_cast<const float4*>(&wxp[j * 8]);
      const float4 w1 = *reinterpret_cast<const float4*>(&wxp[j * 8 + 4]);
      const float2 v = vvA[j];
#define PVM(i, wc) o[i].x = fmaf(wc, v.x, o[i].x); o[i].y = fmaf(wc, v.y, o[i].y);
      PVM(0, w0.x) PVM(1, w0.y) PVM(2, w0.z) PVM(3, w0.w)
      PVM(4, w1.x) PVM(5, w1.y) PVM(6, w1.z) PVM(7, w1.w)
#undef PVM
      if (j & 1) __builtin_amdgcn_sched_barrier(0);
    }
    // ---- PV rows r0+8..r0+15 ----
#pragma unroll
    for (int j = 0; j < 8; ++j) {
      const float4 w0 = *reinterpret_cast<const float4*>(&wxp[(8 + j) * 8]);
      const float4 w1 = *reinterpret_cast<const float4*>(&wxp[(8 + j) * 8 + 4]);
      const float2 v = vvB[j];
#define PVM(i, wc) o[i].x = fmaf(wc, v.x, o[i].x); o[i].y = fmaf(wc, v.y, o[i].y);
      PVM(0, w0.x) PVM(1, w0.y) PVM(2, w0.z) PVM(3, w0.w)
      PVM(4, w1.x) PVM(5, w1.y) PVM(6, w1.z) PVM(7, w1.w)
#undef PVM
      if (j & 1) __builtin_amdgcn_sched_barrier(0);
    }
  }

  // ---- merge the 8 wave-partials (obuf aliases dead qs/wx) ----
  __syncthreads();
  float* obuf = smem;  // [8 waves][8 m][128 d]
#pragma unroll
  for (int mi = 0; mi < 8; ++mi)
    *reinterpret_cast<float2*>(&obuf[wave * 1024 + mi * 128 + dl]) = o[mi];
  if (lane < 8) { mlx[wave][lane][0] = mrun; mlx[wave][lane][1] = lrun; }
  __syncthreads();

  {
    const int mm = t >> 5, seg = t & 31;    // 16 m x 32 segments of 4 d
    const int w0i = mm >> 3, mi = mm & 7;   // wave = rg*2 + w0i holds this m
    float mv[4], lv[4];
#pragma unroll
    for (int r = 0; r < 4; ++r) { mv[r] = mlx[r * 2 + w0i][mi][0]; lv[r] = mlx[r * 2 + w0i][mi][1]; }
    const float mstar = fmaxf(fmaxf(mv[0], mv[1]), fmaxf(mv[2], mv[3]));
    float ew[4];
    float T = 0.f;
#pragma unroll
    for (int r = 0; r < 4; ++r) { ew[r] = __expf(mv[r] - mstar); T = fmaf(lv[r], ew[r], T); }
    float4 acc = make_float4(0.f, 0.f, 0.f, 0.f);
#pragma unroll
    for (int r = 0; r < 4; ++r) {
      const float4 v = *reinterpret_cast<const float4*>(&obuf[(r * 2 + w0i) * 1024 + mi * 128 + seg * 4]);
      acc.x = fmaf(ew[r], v.x, acc.x); acc.y = fmaf(ew[r], v.y, acc.y);
      acc.z = fmaf(ew[r], v.z, acc.z); acc.w = fmaf(ew[r], v.w, acc.w);
    }
    const size_t base = (size_t)((h * NCH1 + c) * M_ + mm) * D_;
    *reinterpret_cast<float4*>(opart + base + seg * 4) = acc;
    if (seg == 0) {
      ml[((size_t)(h * NCH1 + c) * M_ + mm) * 2 + 0] = mstar;
      ml[((size_t)(h * NCH1 + c) * M_ + mm) * 2 + 1] = T;
    }
  }
}

// ---------------------------------------------------------------------------
// Kernel 4: combine 65 chunk partials per (h, m). grid (M_, H_), block 128.
// ---------------------------------------------------------------------------
__global__ __launch_bounds__(128) void k_comb(const float* __restrict__ opart,
                                              const float* __restrict__ ml,
                                              float* __restrict__ out) {
  const int m = blockIdx.x, h = blockIdx.y, t = threadIdx.x;
  __shared__ float Ms[NCH1], Ls[NCH1];
  if (t < NCH1) {
    Ms[t] = ml[((size_t)(h * NCH1 + t) * M_ + m) * 2 + 0];
    Ls[t] = ml[((size_t)(h * NCH1 + t) * M_ + m) * 2 + 1];
  }
  __syncthreads();
  float gM = -3.0e38f;
#pragma unroll
  for (int c2 = 0; c2 < NCH1; ++c2) gM = fmaxf(gM, Ms[c2]);

  const float* __restrict__ ob = opart + (size_t)h * NCH1 * M_ * D_ + (size_t)m * D_ + t;
  float T = 0.f, o0 = 0.f, o1 = 0.f, o2 = 0.f, o3 = 0.f;
#pragma unroll 4
  for (int c2 = 0; c2 < NCH1 - 1; c2 += 4) {
    const float f0 = __expf(Ms[c2 + 0] - gM);
    const float f1 = __expf(Ms[c2 + 1] - gM);
    const float f2 = __expf(Ms[c2 + 2] - gM);
    const float f3 = __expf(Ms[c2 + 3] - gM);
    T = fmaf(Ls[c2 + 0], f0, T); T = fmaf(Ls[c2 + 1], f1, T);
    T = fmaf(Ls[c2 + 2], f2, T); T = fmaf(Ls[c2 + 3], f3, T);
    o0 = fmaf(ob[(size_t)(c2 + 0) * M_ * D_], f0, o0);
    o1 = fmaf(ob[(size_t)(c2 + 1) * M_ * D_], f1, o1);
    o2 = fmaf(ob[(size_t)(c2 + 2) * M_ * D_], f2, o2);
    o3 = fmaf(ob[(size_t)(c2 + 3) * M_ * D_], f3, o3);
  }
  {
    const int c2 = NCH1 - 1;
    const float f = __expf(Ms[c2] - gM);
    T = fmaf(Ls[c2], f, T);
    o0 = fmaf(ob[(size_t)c2 * M_ * D_], f, o0);
  }
  out[(size_t)m * N_ + h * D_ + t] = (o0 + o1 + o2 + o3) / T;
}

// ---------------------------------------------------------------------------
extern "C" void kernel_launch(void* const* d_in, const int* in_sizes, int n_in,
                              void* d_out, int out_size, void* d_ws, size_t ws_size,
                              hipStream_t stream) {
  const float* X  = (const float*)d_in[0];
  const float* Wq = (const float*)d_in[1];
  const float* Wk = (const float*)d_in[2];
  const float* Wv = (const float*)d_in[3];
  const float* cK = (const float*)d_in[4];
  const float* cV = (const float*)d_in[5];
  float* ws    = (float*)d_ws;
  float* qkv   = ws;
  float* part  = ws + PART_OFF;
  float* opart = ws + OPART_OFF;
  float* mlbuf = ws + ML_OFF;
  float* out   = (float*)d_out;

  hipLaunchKernelGGL(k_proj,   dim3(NCB, NIC, 3), dim3(256), 0, stream, X, Wq, Wk, Wv, part);
  hipLaunchKernelGGL(k_reduce, dim3(16, M_, 3),   dim3(256), 0, stream, part, qkv);
  hipLaunchKernelGGL(k_attn,   dim3(NCH1, H_),    dim3(512), 0, stream, cK, cV, qkv, opart, mlbuf);
  hipLaunchKernelGGL(k_comb,   dim3(M_, H_),      dim3(128), 0, stream, opart, mlbuf, out);
}

// Round 13
// 133.050 us; speedup vs baseline: 1.0865x; 1.0865x over previous
//
#include <hip/hip_runtime.h>
#include <hip/hip_bf16.h>
#include <math.h>

// Problem constants
#define M_ 16
#define N_ 4096
#define D_ 128
#define P_ 8192
#define H_ 32

// Projection tiling
#define NIC 32
#define ICH (N_/NIC)
#define NCB 16            // 256-column blocks, 1 col/thread

// Attention chunking: SMALL chunks for TLP (r12 post-mortem: 1 block/CU wall)
#define CHUNK 64
#define NCH (P_/CHUNK)    // 128 cache chunks
#define NCH1 (NCH+1)      // +1 for the 16 appended rows

// Workspace layout (float offsets). opart is bf16 (halves footprint so the
// 129-chunk layout stays within the proven-good 26 MB workspace).
#define QKV_SZ       (3*H_*M_*D_)
#define PART_OFF     (QKV_SZ)
#define OPART_OFF    (QKV_SZ)
#define OPART_HALFSZ ((H_*NCH1*M_*D_)/2)          // bf16 block in f32 slots
#define ML_OFF       (OPART_OFF + OPART_HALFSZ)

// ---------------------------------------------------------------------------
// Kernel 1: partial QKV projection. grid (NCB, NIC, 3), block 256. (as r7)
// ---------------------------------------------------------------------------
__global__ __launch_bounds__(256) void k_proj(const float* __restrict__ X,
                                              const float* __restrict__ Wq,
                                              const float* __restrict__ Wk,
                                              const float* __restrict__ Wv,
                                              float* __restrict__ part) {
  const int mat = blockIdx.z;
  const float* __restrict__ W = (mat == 0) ? Wq : ((mat == 1) ? Wk : Wv);
  const int cb = blockIdx.x, ic = blockIdx.y;
  const int t = threadIdx.x;
  const int j0 = cb * 256 + t;
  const int i0 = ic * ICH;

  __shared__ __align__(16) float XT[ICH][20];

  {
    const int i_l = t & 127, mh = t >> 7;
#pragma unroll
    for (int r = 0; r < 8; ++r)
      XT[i_l][mh * 8 + r] = X[(size_t)(mh * 8 + r) * N_ + i0 + i_l];
  }
  __syncthreads();

  float acc[16];
#pragma unroll
  for (int m = 0; m < 16; ++m) acc[m] = 0.f;

#pragma unroll 8
  for (int i = 0; i < ICH; ++i) {
    const float wv = __builtin_nontemporal_load(W + (size_t)(i0 + i) * N_ + j0);
    float xr[16];
    {
      float4 xv;
      xv = *reinterpret_cast<const float4*>(&XT[i][0]);
      xr[0] = xv.x; xr[1] = xv.y; xr[2] = xv.z; xr[3] = xv.w;
      xv = *reinterpret_cast<const float4*>(&XT[i][4]);
      xr[4] = xv.x; xr[5] = xv.y; xr[6] = xv.z; xr[7] = xv.w;
      xv = *reinterpret_cast<const float4*>(&XT[i][8]);
      xr[8] = xv.x; xr[9] = xv.y; xr[10] = xv.z; xr[11] = xv.w;
      xv = *reinterpret_cast<const float4*>(&XT[i][12]);
      xr[12] = xv.x; xr[13] = xv.y; xr[14] = xv.z; xr[15] = xv.w;
    }
#pragma unroll
    for (int m = 0; m < 16; ++m) acc[m] = fmaf(xr[m], wv, acc[m]);
  }

#pragma unroll
  for (int m = 0; m < 16; ++m)
    __builtin_nontemporal_store(acc[m], part + (size_t)((mat * NIC + ic) * M_ + m) * N_ + j0);
}

// ---------------------------------------------------------------------------
// Kernel 2: reduce partials, RMS-norm q/k, relayout. (as r7)
// ---------------------------------------------------------------------------
__global__ __launch_bounds__(256) void k_reduce(const float* __restrict__ part,
                                                float* __restrict__ qkv) {
  const int mat = blockIdx.z, m = blockIdx.y, nc = blockIdx.x;
  const int t = threadIdx.x;
  const int n = nc * 256 + t;

  float s = 0.f;
#pragma unroll
  for (int ic = 0; ic < NIC; ++ic)
    s += __builtin_nontemporal_load(part + (size_t)((mat * NIC + ic) * M_ + m) * N_ + n);

  float ss = s * s;
#pragma unroll
  for (int off = 1; off < 64; off <<= 1) ss += __shfl_xor(ss, off);
  __shared__ float wsum[4];
  const int wave = t >> 6, lane = t & 63;
  if (lane == 0) wsum[wave] = ss;
  __syncthreads();
  const int half = t >> 7;
  const float tot = wsum[half * 2] + wsum[half * 2 + 1];
  const float scale = (mat < 2) ? rsqrtf(tot * (1.0f / 128.0f)) : 1.0f;

  const int h = n >> 7, d = n & 127;
  qkv[(size_t)((mat * H_ + h) * M_ + m) * D_ + d] = s * scale;
}

// ---------------------------------------------------------------------------
// fold8: reduce a[0..7] over the 8 dq-lanes (lane bits 0..2).
// ---------------------------------------------------------------------------
__device__ __forceinline__ float fold8(float a[8], int dq) {
#pragma unroll
  for (int i = 0; i < 4; ++i) {
    const float send = (dq & 4) ? a[i] : a[i + 4];
    const float recv = __shfl_xor(send, 4);
    a[i] = ((dq & 4) ? a[i + 4] : a[i]) + recv;
  }
#pragma unroll
  for (int i = 0; i < 2; ++i) {
    const float send = (dq & 2) ? a[i] : a[i + 2];
    const float recv = __shfl_xor(send, 2);
    a[i] = ((dq & 2) ? a[i + 2] : a[i]) + recv;
  }
  {
    const float send = (dq & 1) ? a[0] : a[1];
    const float recv = __shfl_xor(send, 1);
    a[0] = ((dq & 1) ? a[1] : a[0]) + recv;
  }
  return a[0];
}

__device__ __forceinline__ unsigned pk2(float a, float b) {
  __hip_bfloat16 ha = __float2bfloat16(a), hb = __float2bfloat16(b);
  const unsigned short ua = *reinterpret_cast<unsigned short*>(&ha);
  const unsigned short ub = *reinterpret_cast<unsigned short*>(&hb);
  return (unsigned)ua | ((unsigned)ub << 16);
}

// ---------------------------------------------------------------------------
// Kernel 3: p-split attention, small blocks for TLP. grid (NCH1, H_),
// block 256 = 4 waves = 2 row-groups x 2 m-halves, chunk = 64 rows.
// r12 post-mortem: occupancy ~= ONE 8-wave block/CU -> latency-bound at
// 2.4 TB/s effective. 4128 blocks x 18 KB LDS x 256 thr -> several
// blocks/CU resident. Per-wave arithmetic identical to r12 (passed 0.0078)
// except vv is issued at batch HEAD (covered by ~1000cy of score compute).
// opart written in bf16 (keeps 129-partial layout inside 26 MB ws).
// ---------------------------------------------------------------------------
__global__ __launch_bounds__(256, 2) void k_attn(const float* __restrict__ cacheK,
                                                 const float* __restrict__ cacheV,
                                                 const float* __restrict__ qkv,
                                                 __hip_bfloat16* __restrict__ opart,
                                                 float* __restrict__ ml) {
  const int c = blockIdx.x, h = blockIdx.y;
  const int t = threadIdx.x;
  const int wave = t >> 6, lane = t & 63;
  const int valid = (c < NCH) ? CHUNK : M_;
  const float* __restrict__ Ksrc = (c < NCH)
      ? (cacheK + ((size_t)h * P_ + (size_t)c * CHUNK) * D_)
      : (qkv + (size_t)((1 * H_ + h) * M_) * D_);
  const float* __restrict__ Vsrc = (c < NCH)
      ? (cacheV + ((size_t)h * P_ + (size_t)c * CHUNK) * D_)
      : (qkv + (size_t)((2 * H_ + h) * M_) * D_);

  __shared__ __align__(16) float smem[4096];    // 16 KB: qs[2048] / obuf[4096]
  __shared__ __align__(16) float wx[4 * 128];   // 2 KB wave-private strips
  __shared__ __align__(16) float mlx[4][8][2];  // per-wave (m, l)

  float* qs = smem;                 // [16][128]
  float* wxp = wx + wave * 128;     // [16 rows][8 m]

  // stage q (16x128)
  {
    const float4* src = reinterpret_cast<const float4*>(qkv + (size_t)(h * M_) * D_);
    reinterpret_cast<float4*>(qs)[t] = src[t];
    reinterpret_cast<float4*>(qs)[t + 256] = src[t + 256];
  }
  __syncthreads();

  const int pg = lane >> 3, dq = lane & 7;
  const int dl = lane * 2;
  const int rg = wave >> 1, mbase = (wave & 1) * 8;
  const int rbase = rg * 32;
  int rc = valid - rbase; rc = (rc < 0) ? 0 : ((rc > 32) ? 32 : rc);
  const int nb = rc >> 4;   // 16-row batches: 2, 1, or 0

  float mrun = -3.0e38f, lrun = 0.f;
  float2 o[8];
#pragma unroll
  for (int mi = 0; mi < 8; ++mi) o[mi] = make_float2(0.f, 0.f);

  // K register block: kk[0..3] = row r0+pg, kk[4..7] = row r0+8+pg
  float4 kk[8];
  if (nb > 0) {
    const float* ka = Ksrc + (size_t)(rbase + pg) * D_ + dq * 4;
    kk[0] = *reinterpret_cast<const float4*>(ka);
    kk[1] = *reinterpret_cast<const float4*>(ka + 32);
    kk[2] = *reinterpret_cast<const float4*>(ka + 64);
    kk[3] = *reinterpret_cast<const float4*>(ka + 96);
    const float* kb = Ksrc + (size_t)(rbase + 8 + pg) * D_ + dq * 4;
    kk[4] = *reinterpret_cast<const float4*>(kb);
    kk[5] = *reinterpret_cast<const float4*>(kb + 32);
    kk[6] = *reinterpret_cast<const float4*>(kb + 64);
    kk[7] = *reinterpret_cast<const float4*>(kb + 96);
  }

#pragma unroll 1
  for (int b = 0; b < nb; ++b) {
    const int r0 = rbase + b * 16;

    // ---- V loads issued at batch HEAD (covered by the score FMAs below) ----
    float2 vvA[8], vvB[8];
#pragma unroll
    for (int j = 0; j < 8; ++j)
      vvA[j] = *reinterpret_cast<const float2*>(Vsrc + (size_t)(r0 + j) * D_ + dl);
#pragma unroll
    for (int j = 0; j < 8; ++j)
      vvB[j] = *reinterpret_cast<const float2*>(Vsrc + (size_t)(r0 + 8 + j) * D_ + dl);

    // ---- scores, fused over both row-groups (one qv read serves kA,kB) ----
    float aA[8], aB[8];
#pragma unroll
    for (int mi = 0; mi < 8; ++mi) {
      const float* qrow = qs + (mbase + mi) * D_ + dq * 4;
      const float4 q0 = *reinterpret_cast<const float4*>(qrow);
      const float4 q1 = *reinterpret_cast<const float4*>(qrow + 32);
      const float4 q2 = *reinterpret_cast<const float4*>(qrow + 64);
      const float4 q3 = *reinterpret_cast<const float4*>(qrow + 96);
      float sa, sb;
      sa = q0.x * kk[0].x;
      sa = fmaf(q0.y, kk[0].y, sa); sa = fmaf(q0.z, kk[0].z, sa); sa = fmaf(q0.w, kk[0].w, sa);
      sa = fmaf(q1.x, kk[1].x, sa); sa = fmaf(q1.y, kk[1].y, sa);
      sa = fmaf(q1.z, kk[1].z, sa); sa = fmaf(q1.w, kk[1].w, sa);
      sa = fmaf(q2.x, kk[2].x, sa); sa = fmaf(q2.y, kk[2].y, sa);
      sa = fmaf(q2.z, kk[2].z, sa); sa = fmaf(q2.w, kk[2].w, sa);
      sa = fmaf(q3.x, kk[3].x, sa); sa = fmaf(q3.y, kk[3].y, sa);
      sa = fmaf(q3.z, kk[3].z, sa); sa = fmaf(q3.w, kk[3].w, sa);
      sb = q0.x * kk[4].x;
      sb = fmaf(q0.y, kk[4].y, sb); sb = fmaf(q0.z, kk[4].z, sb); sb = fmaf(q0.w, kk[4].w, sb);
      sb = fmaf(q1.x, kk[5].x, sb); sb = fmaf(q1.y, kk[5].y, sb);
      sb = fmaf(q1.z, kk[5].z, sb); sb = fmaf(q1.w, kk[5].w, sb);
      sb = fmaf(q2.x, kk[6].x, sb); sb = fmaf(q2.y, kk[6].y, sb);
      sb = fmaf(q2.z, kk[6].z, sb); sb = fmaf(q2.w, kk[6].w, sb);
      sb = fmaf(q3.x, kk[7].x, sb); sb = fmaf(q3.y, kk[7].y, sb);
      sb = fmaf(q3.z, kk[7].z, sb); sb = fmaf(q3.w, kk[7].w, sb);
      aA[mi] = sa; aB[mi] = sb;
      __builtin_amdgcn_sched_barrier(0);  // cap qv ds_read clustering (r9 lesson)
    }

    // ---- cross-batch K prefetch into the now-dead kk registers ----
    {
      int rn = r0 + 16 + pg;
      rn = (rn < valid) ? rn : (valid - 1);   // phantom on last batch
      const float* ka = Ksrc + (size_t)rn * D_ + dq * 4;
      kk[0] = *reinterpret_cast<const float4*>(ka);
      kk[1] = *reinterpret_cast<const float4*>(ka + 32);
      kk[2] = *reinterpret_cast<const float4*>(ka + 64);
      kk[3] = *reinterpret_cast<const float4*>(ka + 96);
      int rn2 = r0 + 24 + pg;
      rn2 = (rn2 < valid) ? rn2 : (valid - 1);
      const float* kb = Ksrc + (size_t)rn2 * D_ + dq * 4;
      kk[4] = *reinterpret_cast<const float4*>(kb);
      kk[5] = *reinterpret_cast<const float4*>(kb + 32);
      kk[6] = *reinterpret_cast<const float4*>(kb + 64);
      kk[7] = *reinterpret_cast<const float4*>(kb + 96);
    }

    // ---- folds + online softmax over the 16 rows ----
    const float sA = fold8(aA, dq);
    const float sB = fold8(aB, dq);
    float tmax = fmaxf(sA, sB);
    tmax = fmaxf(tmax, __shfl_xor(tmax, 8));
    tmax = fmaxf(tmax, __shfl_xor(tmax, 16));
    tmax = fmaxf(tmax, __shfl_xor(tmax, 32));
    const float mnew = fmaxf(mrun, tmax);
    const float fc = __expf(mrun - mnew);
    mrun = mnew;
    const float wA = __expf(sA - mnew);
    const float wB = __expf(sB - mnew);
    float rs = wA + wB;
    rs += __shfl_xor(rs, 8); rs += __shfl_xor(rs, 16); rs += __shfl_xor(rs, 32);
    lrun = lrun * fc + rs;

    // publish weights (wave-private strip; same-wave RAW ordered by lgkmcnt)
    wxp[pg * 8 + dq] = wA;
    wxp[(8 + pg) * 8 + dq] = wB;

    // ---- rescale o by this batch's factor (per-m fc gathered via shfl) ----
#pragma unroll
    for (int mi = 0; mi < 8; ++mi) {
      const float fcm = __shfl(fc, (lane & 56) | mi);
      o[mi].x *= fcm; o[mi].y *= fcm;
    }

    // ---- PV rows r0..r0+7 ----
#pragma unroll
    for (int j = 0; j < 8; ++j) {
      const float4 w0 = *reinterpret_cast<const float4*>(&wxp[j * 8]);
      const float4 w1 = *reinterpret_cast<const float4*>(&wxp[j * 8 + 4]);
      const float2 v = vvA[j];
#define PVM(i, wc) o[i].x = fmaf(wc, v.x, o[i].x); o[i].y = fmaf(wc, v.y, o[i].y);
      PVM(0, w0.x) PVM(1, w0.y) PVM(2, w0.z) PVM(3, w0.w)
      PVM(4, w1.x) PVM(5, w1.y) PVM(6, w1.z) PVM(7, w1.w)
#undef PVM
      if (j & 1) __builtin_amdgcn_sched_barrier(0);
    }
    // ---- PV rows r0+8..r0+15 ----
#pragma unroll
    for (int j = 0; j < 8; ++j) {
      const float4 w0 = *reinterpret_cast<const float4*>(&wxp[(8 + j) * 8]);
      const float4 w1 = *reinterpret_cast<const float4*>(&wxp[(8 + j) * 8 + 4]);
      const float2 v = vvB[j];
#define PVM(i, wc) o[i].x = fmaf(wc, v.x, o[i].x); o[i].y = fmaf(wc, v.y, o[i].y);
      PVM(0, w0.x) PVM(1, w0.y) PVM(2, w0.z) PVM(3, w0.w)
      PVM(4, w1.x) PVM(5, w1.y) PVM(6, w1.z) PVM(7, w1.w)
#undef PVM
      if (j & 1) __builtin_amdgcn_sched_barrier(0);
    }
  }

  // ---- merge the 4 wave-partials (obuf aliases dead qs/wx region) ----
  __syncthreads();
  float* obuf = smem;  // [4 waves][8 m][128 d] = 4096 floats
#pragma unroll
  for (int mi = 0; mi < 8; ++mi)
    *reinterpret_cast<float2*>(&obuf[wave * 1024 + mi * 128 + dl]) = o[mi];
  if (lane < 8) { mlx[wave][lane][0] = mrun; mlx[wave][lane][1] = lrun; }
  __syncthreads();

  {
    const int mm = t >> 4, seg = t & 15;    // 16 m x 16 segments of 8 d
    const int mh = mm >> 3, mi = mm & 7;    // partials in waves mh and 2+mh
    const float m0v = mlx[mh][mi][0], m1v = mlx[2 + mh][mi][0];
    const float mstar = fmaxf(m0v, m1v);
    const float e0 = __expf(m0v - mstar), e1 = __expf(m1v - mstar);
    const float T = mlx[mh][mi][1] * e0 + mlx[2 + mh][mi][1] * e1;
    const float4 a0 = *reinterpret_cast<const float4*>(&obuf[mh * 1024 + mi * 128 + seg * 8]);
    const float4 a1 = *reinterpret_cast<const float4*>(&obuf[mh * 1024 + mi * 128 + seg * 8 + 4]);
    const float4 b0 = *reinterpret_cast<const float4*>(&obuf[(2 + mh) * 1024 + mi * 128 + seg * 8]);
    const float4 b1 = *reinterpret_cast<const float4*>(&obuf[(2 + mh) * 1024 + mi * 128 + seg * 8 + 4]);
    float r0 = e0 * a0.x + e1 * b0.x, r1 = e0 * a0.y + e1 * b0.y;
    float r2 = e0 * a0.z + e1 * b0.z, r3 = e0 * a0.w + e1 * b0.w;
    float r4 = e0 * a1.x + e1 * b1.x, r5 = e0 * a1.y + e1 * b1.y;
    float r6 = e0 * a1.z + e1 * b1.z, r7 = e0 * a1.w + e1 * b1.w;
    uint4 pk;
    pk.x = pk2(r0, r1); pk.y = pk2(r2, r3); pk.z = pk2(r4, r5); pk.w = pk2(r6, r7);
    const size_t base = ((size_t)(h * NCH1 + c) * M_ + mm) * D_ + seg * 8;
    *reinterpret_cast<uint4*>(opart + base) = pk;
    if (seg == 0) {
      ml[((size_t)(h * NCH1 + c) * M_ + mm) * 2 + 0] = mstar;
      ml[((size_t)(h * NCH1 + c) * M_ + mm) * 2 + 1] = T;
    }
  }
}

// ---------------------------------------------------------------------------
// Kernel 4: combine 129 chunk partials per (h, m). grid (M_, H_), block 128.
// bf16 partials; Ms/Ls loop-loaded (129 > 128 threads).
// ---------------------------------------------------------------------------
__global__ __launch_bounds__(128) void k_comb(const __hip_bfloat16* __restrict__ opart,
                                              const float* __restrict__ ml,
                                              float* __restrict__ out) {
  const int m = blockIdx.x, h = blockIdx.y, t = threadIdx.x;
  __shared__ float Ms[NCH1], Ls[NCH1];
  for (int i = t; i < NCH1; i += 128) {
    Ms[i] = ml[((size_t)(h * NCH1 + i) * M_ + m) * 2 + 0];
    Ls[i] = ml[((size_t)(h * NCH1 + i) * M_ + m) * 2 + 1];
  }
  __syncthreads();
  float gM = -3.0e38f;
#pragma unroll 8
  for (int c2 = 0; c2 < NCH1; ++c2) gM = fmaxf(gM, Ms[c2]);

  const __hip_bfloat16* __restrict__ ob =
      opart + (size_t)h * NCH1 * M_ * D_ + (size_t)m * D_ + t;
  float T = 0.f, o0 = 0.f, o1 = 0.f, o2 = 0.f, o3 = 0.f;
#pragma unroll 4
  for (int c2 = 0; c2 < NCH1 - 1; c2 += 4) {
    const float f0 = __expf(Ms[c2 + 0] - gM);
    const float f1 = __expf(Ms[c2 + 1] - gM);
    const float f2 = __expf(Ms[c2 + 2] - gM);
    const float f3 = __expf(Ms[c2 + 3] - gM);
    T = fmaf(Ls[c2 + 0], f0, T); T = fmaf(Ls[c2 + 1], f1, T);
    T = fmaf(Ls[c2 + 2], f2, T); T = fmaf(Ls[c2 + 3], f3, T);
    o0 = fmaf(__bfloat162float(ob[(size_t)(c2 + 0) * M_ * D_]), f0, o0);
    o1 = fmaf(__bfloat162float(ob[(size_t)(c2 + 1) * M_ * D_]), f1, o1);
    o2 = fmaf(__bfloat162float(ob[(size_t)(c2 + 2) * M_ * D_]), f2, o2);
    o3 = fmaf(__bfloat162float(ob[(size_t)(c2 + 3) * M_ * D_]), f3, o3);
  }
  {
    const int c2 = NCH1 - 1;
    const float f = __expf(Ms[c2] - gM);
    T = fmaf(Ls[c2], f, T);
    o0 = fmaf(__bfloat162float(ob[(size_t)c2 * M_ * D_]), f, o0);
  }
  out[(size_t)m * N_ + h * D_ + t] = (o0 + o1 + o2 + o3) / T;
}

// ---------------------------------------------------------------------------
extern "C" void kernel_launch(void* const* d_in, const int* in_sizes, int n_in,
                              void* d_out, int out_size, void* d_ws, size_t ws_size,
                              hipStream_t stream) {
  const float* X  = (const float*)d_in[0];
  const float* Wq = (const float*)d_in[1];
  const float* Wk = (const float*)d_in[2];
  const float* Wv = (const float*)d_in[3];
  const float* cK = (const float*)d_in[4];
  const float* cV = (const float*)d_in[5];
  float* ws    = (float*)d_ws;
  float* qkv   = ws;
  float* part  = ws + PART_OFF;
  __hip_bfloat16* opart = (__hip_bfloat16*)(ws + OPART_OFF);
  float* mlbuf = ws + ML_OFF;
  float* out   = (float*)d_out;

  hipLaunchKernelGGL(k_proj,   dim3(NCB, NIC, 3), dim3(256), 0, stream, X, Wq, Wk, Wv, part);
  hipLaunchKernelGGL(k_reduce, dim3(16, M_, 3),   dim3(256), 0, stream, part, qkv);
  hipLaunchKernelGGL(k_attn,   dim3(NCH1, H_),    dim3(256), 0, stream, cK, cV, qkv, opart, mlbuf);
  hipLaunchKernelGGL(k_comb,   dim3(M_, H_),      dim3(128), 0, stream, opart, mlbuf, out);
}

// Round 14
// 124.391 us; speedup vs baseline: 1.1621x; 1.0696x over previous
//
#include <hip/hip_runtime.h>
#include <hip/hip_bf16.h>
#include <math.h>

// Problem constants
#define M_ 16
#define N_ 4096
#define D_ 128
#define P_ 8192
#define H_ 32

// Projection tiling
#define NIC 32
#define ICH (N_/NIC)
#define NCB 16            // 256-column blocks, 1 col/thread

// Attention chunking
#define CHUNK 64
#define NCH (P_/CHUNK)    // 128 cache chunks
#define NCH1 (NCH+1)      // +1 for the 16 appended rows

// Workspace layout (float offsets). opart is bf16.
#define QKV_SZ       (3*H_*M_*D_)
#define PART_OFF     (QKV_SZ)
#define OPART_OFF    (QKV_SZ)
#define OPART_HALFSZ ((H_*NCH1*M_*D_)/2)
#define ML_OFF       (OPART_OFF + OPART_HALFSZ)

// ---------------------------------------------------------------------------
// Kernel 1: partial QKV projection. grid (NCB, NIC, 3), block 256. (as r13)
// ---------------------------------------------------------------------------
__global__ __launch_bounds__(256) void k_proj(const float* __restrict__ X,
                                              const float* __restrict__ Wq,
                                              const float* __restrict__ Wk,
                                              const float* __restrict__ Wv,
                                              float* __restrict__ part) {
  const int mat = blockIdx.z;
  const float* __restrict__ W = (mat == 0) ? Wq : ((mat == 1) ? Wk : Wv);
  const int cb = blockIdx.x, ic = blockIdx.y;
  const int t = threadIdx.x;
  const int j0 = cb * 256 + t;
  const int i0 = ic * ICH;

  __shared__ __align__(16) float XT[ICH][20];

  {
    const int i_l = t & 127, mh = t >> 7;
#pragma unroll
    for (int r = 0; r < 8; ++r)
      XT[i_l][mh * 8 + r] = X[(size_t)(mh * 8 + r) * N_ + i0 + i_l];
  }
  __syncthreads();

  float acc[16];
#pragma unroll
  for (int m = 0; m < 16; ++m) acc[m] = 0.f;

#pragma unroll 8
  for (int i = 0; i < ICH; ++i) {
    const float wv = __builtin_nontemporal_load(W + (size_t)(i0 + i) * N_ + j0);
    float xr[16];
    {
      float4 xv;
      xv = *reinterpret_cast<const float4*>(&XT[i][0]);
      xr[0] = xv.x; xr[1] = xv.y; xr[2] = xv.z; xr[3] = xv.w;
      xv = *reinterpret_cast<const float4*>(&XT[i][4]);
      xr[4] = xv.x; xr[5] = xv.y; xr[6] = xv.z; xr[7] = xv.w;
      xv = *reinterpret_cast<const float4*>(&XT[i][8]);
      xr[8] = xv.x; xr[9] = xv.y; xr[10] = xv.z; xr[11] = xv.w;
      xv = *reinterpret_cast<const float4*>(&XT[i][12]);
      xr[12] = xv.x; xr[13] = xv.y; xr[14] = xv.z; xr[15] = xv.w;
    }
#pragma unroll
    for (int m = 0; m < 16; ++m) acc[m] = fmaf(xr[m], wv, acc[m]);
  }

#pragma unroll
  for (int m = 0; m < 16; ++m)
    __builtin_nontemporal_store(acc[m], part + (size_t)((mat * NIC + ic) * M_ + m) * N_ + j0);
}

// ---------------------------------------------------------------------------
// Kernel 2: reduce partials, RMS-norm q/k, relayout. (as r13)
// ---------------------------------------------------------------------------
__global__ __launch_bounds__(256) void k_reduce(const float* __restrict__ part,
                                                float* __restrict__ qkv) {
  const int mat = blockIdx.z, m = blockIdx.y, nc = blockIdx.x;
  const int t = threadIdx.x;
  const int n = nc * 256 + t;

  float s = 0.f;
#pragma unroll
  for (int ic = 0; ic < NIC; ++ic)
    s += __builtin_nontemporal_load(part + (size_t)((mat * NIC + ic) * M_ + m) * N_ + n);

  float ss = s * s;
#pragma unroll
  for (int off = 1; off < 64; off <<= 1) ss += __shfl_xor(ss, off);
  __shared__ float wsum[4];
  const int wave = t >> 6, lane = t & 63;
  if (lane == 0) wsum[wave] = ss;
  __syncthreads();
  const int half = t >> 7;
  const float tot = wsum[half * 2] + wsum[half * 2 + 1];
  const float scale = (mat < 2) ? rsqrtf(tot * (1.0f / 128.0f)) : 1.0f;

  const int h = n >> 7, d = n & 127;
  qkv[(size_t)((mat * H_ + h) * M_ + m) * D_ + d] = s * scale;
}

// ---------------------------------------------------------------------------
// fold8: reduce a[0..7] over the 8 dq-lanes (lane bits 0..2).
// ---------------------------------------------------------------------------
__device__ __forceinline__ float fold8(float a[8], int dq) {
#pragma unroll
  for (int i = 0; i < 4; ++i) {
    const float send = (dq & 4) ? a[i] : a[i + 4];
    const float recv = __shfl_xor(send, 4);
    a[i] = ((dq & 4) ? a[i + 4] : a[i]) + recv;
  }
#pragma unroll
  for (int i = 0; i < 2; ++i) {
    const float send = (dq & 2) ? a[i] : a[i + 2];
    const float recv = __shfl_xor(send, 2);
    a[i] = ((dq & 2) ? a[i + 2] : a[i]) + recv;
  }
  {
    const float send = (dq & 1) ? a[0] : a[1];
    const float recv = __shfl_xor(send, 1);
    a[0] = ((dq & 1) ? a[1] : a[0]) + recv;
  }
  return a[0];
}

__device__ __forceinline__ unsigned pk2(float a, float b) {
  __hip_bfloat16 ha = __float2bfloat16(a), hb = __float2bfloat16(b);
  const unsigned short ua = *reinterpret_cast<unsigned short*>(&ha);
  const unsigned short ub = *reinterpret_cast<unsigned short*>(&hb);
  return (unsigned)ua | ((unsigned)ub << 16);
}

// ---------------------------------------------------------------------------
// Kernel 3: p-split attention — OCCUPANCY-HINT EXPERIMENT.
// Session-wide pattern: OccupancyPercent tracks launch_bounds' 2nd arg
// (min_waves=4 -> ~40%, =2 -> ~20%) across all structures, never tracking
// LDS/VGPR caps. Hypothesis: the waves-per-eu hint acts as an occupancy
// target/max on this toolchain. Fix: __launch_bounds__(256) +
// amdgpu_waves_per_eu(4, 8): min 4 -> VGPR cap 128 (demand ~75-90, no r3/
// r5/r10-style spill); max 8 explicitly allows full residency.
// Batches shrunk to 8 rows (kk[4], vv[8]) to keep demand well under 128.
// No cross-batch prefetch (r12 proved it null). Arithmetic = r13 (passed).
// ---------------------------------------------------------------------------
__global__ __attribute__((amdgpu_waves_per_eu(4, 8)))
__launch_bounds__(256) void k_attn(const float* __restrict__ cacheK,
                                   const float* __restrict__ cacheV,
                                   const float* __restrict__ qkv,
                                   __hip_bfloat16* __restrict__ opart,
                                   float* __restrict__ ml) {
  const int c = blockIdx.x, h = blockIdx.y;
  const int t = threadIdx.x;
  const int wave = t >> 6, lane = t & 63;
  const int valid = (c < NCH) ? CHUNK : M_;
  const float* __restrict__ Ksrc = (c < NCH)
      ? (cacheK + ((size_t)h * P_ + (size_t)c * CHUNK) * D_)
      : (qkv + (size_t)((1 * H_ + h) * M_) * D_);
  const float* __restrict__ Vsrc = (c < NCH)
      ? (cacheV + ((size_t)h * P_ + (size_t)c * CHUNK) * D_)
      : (qkv + (size_t)((2 * H_ + h) * M_) * D_);

  __shared__ __align__(16) float smem[4096];    // 16 KB: qs[2048] / obuf[4096]
  __shared__ __align__(16) float wx[4 * 128];   // 2 KB wave-private strips
  __shared__ __align__(16) float mlx[4][8][2];  // per-wave (m, l)

  float* qs = smem;                 // [16][128]
  float* wxp = wx + wave * 128;

  // stage q (16x128)
  {
    const float4* src = reinterpret_cast<const float4*>(qkv + (size_t)(h * M_) * D_);
    reinterpret_cast<float4*>(qs)[t] = src[t];
    reinterpret_cast<float4*>(qs)[t + 256] = src[t + 256];
  }
  __syncthreads();

  const int pg = lane >> 3, dq = lane & 7;
  const int dl = lane * 2;
  const int rg = wave >> 1, mbase = (wave & 1) * 8;
  const int rbase = rg * 32;
  int rc = valid - rbase; rc = (rc < 0) ? 0 : ((rc > 32) ? 32 : rc);
  const int nb = rc >> 3;   // 8-row batches: 0, 2, or 4

  float mrun = -3.0e38f, lrun = 0.f;
  float2 o[8];
#pragma unroll
  for (int mi = 0; mi < 8; ++mi) o[mi] = make_float2(0.f, 0.f);

#pragma unroll 1
  for (int b = 0; b < nb; ++b) {
    const int r0 = rbase + b * 8;

    // ---- K loads FIRST (scores' vmcnt wait covers only these 4) ----
    float4 kk0, kk1, kk2, kk3;
    {
      const float* ka = Ksrc + (size_t)(r0 + pg) * D_ + dq * 4;
      kk0 = *reinterpret_cast<const float4*>(ka);
      kk1 = *reinterpret_cast<const float4*>(ka + 32);
      kk2 = *reinterpret_cast<const float4*>(ka + 64);
      kk3 = *reinterpret_cast<const float4*>(ka + 96);
    }
    // ---- V loads (outstanding through scores + fold + softmax) ----
    float2 vv[8];
#pragma unroll
    for (int j = 0; j < 8; ++j)
      vv[j] = *reinterpret_cast<const float2*>(Vsrc + (size_t)(r0 + j) * D_ + dl);

    // ---- scores: a[mi] = q[mbase+mi] . K[r0+pg] (dq d-slice) ----
    float a[8];
#pragma unroll
    for (int mi = 0; mi < 8; ++mi) {
      const float* qrow = qs + (mbase + mi) * D_ + dq * 4;
      const float4 q0 = *reinterpret_cast<const float4*>(qrow);
      const float4 q1 = *reinterpret_cast<const float4*>(qrow + 32);
      const float4 q2 = *reinterpret_cast<const float4*>(qrow + 64);
      const float4 q3 = *reinterpret_cast<const float4*>(qrow + 96);
      float s;
      s = q0.x * kk0.x;
      s = fmaf(q0.y, kk0.y, s); s = fmaf(q0.z, kk0.z, s); s = fmaf(q0.w, kk0.w, s);
      s = fmaf(q1.x, kk1.x, s); s = fmaf(q1.y, kk1.y, s);
      s = fmaf(q1.z, kk1.z, s); s = fmaf(q1.w, kk1.w, s);
      s = fmaf(q2.x, kk2.x, s); s = fmaf(q2.y, kk2.y, s);
      s = fmaf(q2.z, kk2.z, s); s = fmaf(q2.w, kk2.w, s);
      s = fmaf(q3.x, kk3.x, s); s = fmaf(q3.y, kk3.y, s);
      s = fmaf(q3.z, kk3.z, s); s = fmaf(q3.w, kk3.w, s);
      a[mi] = s;
      __builtin_amdgcn_sched_barrier(0);  // cap qv ds_read clustering (r9 lesson)
    }

    // ---- fold + online softmax over the 8 rows (pg lanes, bits 3..5) ----
    const float sA = fold8(a, dq);
    float tmax = sA;
    tmax = fmaxf(tmax, __shfl_xor(tmax, 8));
    tmax = fmaxf(tmax, __shfl_xor(tmax, 16));
    tmax = fmaxf(tmax, __shfl_xor(tmax, 32));
    const float mnew = fmaxf(mrun, tmax);
    const float fc = __expf(mrun - mnew);
    mrun = mnew;
    const float wA = __expf(sA - mnew);
    float rs = wA;
    rs += __shfl_xor(rs, 8); rs += __shfl_xor(rs, 16); rs += __shfl_xor(rs, 32);
    lrun = lrun * fc + rs;

    // publish weights (wave-private strip; same-wave RAW ordered by lgkmcnt)
    wxp[pg * 8 + dq] = wA;

    // ---- rescale o (per-m fc gathered via shfl) ----
#pragma unroll
    for (int mi = 0; mi < 8; ++mi) {
      const float fcm = __shfl(fc, (lane & 56) | mi);
      o[mi].x *= fcm; o[mi].y *= fcm;
    }

    // ---- PV over the 8 rows ----
#pragma unroll
    for (int j = 0; j < 8; ++j) {
      const float4 w0 = *reinterpret_cast<const float4*>(&wxp[j * 8]);
      const float4 w1 = *reinterpret_cast<const float4*>(&wxp[j * 8 + 4]);
      const float2 v = vv[j];
#define PVM(i, wc) o[i].x = fmaf(wc, v.x, o[i].x); o[i].y = fmaf(wc, v.y, o[i].y);
      PVM(0, w0.x) PVM(1, w0.y) PVM(2, w0.z) PVM(3, w0.w)
      PVM(4, w1.x) PVM(5, w1.y) PVM(6, w1.z) PVM(7, w1.w)
#undef PVM
      if (j & 1) __builtin_amdgcn_sched_barrier(0);
    }
  }

  // ---- merge the 4 wave-partials (obuf aliases dead qs region) ----
  __syncthreads();
  float* obuf = smem;  // [4 waves][8 m][128 d]
#pragma unroll
  for (int mi = 0; mi < 8; ++mi)
    *reinterpret_cast<float2*>(&obuf[wave * 1024 + mi * 128 + dl]) = o[mi];
  if (lane < 8) { mlx[wave][lane][0] = mrun; mlx[wave][lane][1] = lrun; }
  __syncthreads();

  {
    const int mm = t >> 4, seg = t & 15;    // 16 m x 16 segments of 8 d
    const int mh = mm >> 3, mi = mm & 7;    // partials live in waves mh and 2+mh
    const float m0v = mlx[mh][mi][0], m1v = mlx[2 + mh][mi][0];
    const float mstar = fmaxf(m0v, m1v);
    const float e0 = __expf(m0v - mstar), e1 = __expf(m1v - mstar);
    const float T = mlx[mh][mi][1] * e0 + mlx[2 + mh][mi][1] * e1;
    const float4 a0 = *reinterpret_cast<const float4*>(&obuf[mh * 1024 + mi * 128 + seg * 8]);
    const float4 a1 = *reinterpret_cast<const float4*>(&obuf[mh * 1024 + mi * 128 + seg * 8 + 4]);
    const float4 b0 = *reinterpret_cast<const float4*>(&obuf[(2 + mh) * 1024 + mi * 128 + seg * 8]);
    const float4 b1 = *reinterpret_cast<const float4*>(&obuf[(2 + mh) * 1024 + mi * 128 + seg * 8 + 4]);
    float r0 = e0 * a0.x + e1 * b0.x, r1 = e0 * a0.y + e1 * b0.y;
    float r2 = e0 * a0.z + e1 * b0.z, r3 = e0 * a0.w + e1 * b0.w;
    float r4 = e0 * a1.x + e1 * b1.x, r5 = e0 * a1.y + e1 * b1.y;
    float r6 = e0 * a1.z + e1 * b1.z, r7 = e0 * a1.w + e1 * b1.w;
    uint4 pk;
    pk.x = pk2(r0, r1); pk.y = pk2(r2, r3); pk.z = pk2(r4, r5); pk.w = pk2(r6, r7);
    const size_t base = ((size_t)(h * NCH1 + c) * M_ + mm) * D_ + seg * 8;
    *reinterpret_cast<uint4*>(opart + base) = pk;
    if (seg == 0) {
      ml[((size_t)(h * NCH1 + c) * M_ + mm) * 2 + 0] = mstar;
      ml[((size_t)(h * NCH1 + c) * M_ + mm) * 2 + 1] = T;
    }
  }
}

// ---------------------------------------------------------------------------
// Kernel 4: combine 129 chunk partials per (h, m). grid (M_, H_), block 128.
// ---------------------------------------------------------------------------
__global__ __launch_bounds__(128) void k_comb(const __hip_bfloat16* __restrict__ opart,
                                              const float* __restrict__ ml,
                                              float* __restrict__ out) {
  const int m = blockIdx.x, h = blockIdx.y, t = threadIdx.x;
  __shared__ float Ms[NCH1], Ls[NCH1];
  for (int i = t; i < NCH1; i += 128) {
    Ms[i] = ml[((size_t)(h * NCH1 + i) * M_ + m) * 2 + 0];
    Ls[i] = ml[((size_t)(h * NCH1 + i) * M_ + m) * 2 + 1];
  }
  __syncthreads();
  float gM = -3.0e38f;
#pragma unroll 8
  for (int c2 = 0; c2 < NCH1; ++c2) gM = fmaxf(gM, Ms[c2]);

  const __hip_bfloat16* __restrict__ ob =
      opart + (size_t)h * NCH1 * M_ * D_ + (size_t)m * D_ + t;
  float T = 0.f, o0 = 0.f, o1 = 0.f, o2 = 0.f, o3 = 0.f;
#pragma unroll 4
  for (int c2 = 0; c2 < NCH1 - 1; c2 += 4) {
    const float f0 = __expf(Ms[c2 + 0] - gM);
    const float f1 = __expf(Ms[c2 + 1] - gM);
    const float f2 = __expf(Ms[c2 + 2] - gM);
    const float f3 = __expf(Ms[c2 + 3] - gM);
    T = fmaf(Ls[c2 + 0], f0, T); T = fmaf(Ls[c2 + 1], f1, T);
    T = fmaf(Ls[c2 + 2], f2, T); T = fmaf(Ls[c2 + 3], f3, T);
    o0 = fmaf(__bfloat162float(ob[(size_t)(c2 + 0) * M_ * D_]), f0, o0);
    o1 = fmaf(__bfloat162float(ob[(size_t)(c2 + 1) * M_ * D_]), f1, o1);
    o2 = fmaf(__bfloat162float(ob[(size_t)(c2 + 2) * M_ * D_]), f2, o2);
    o3 = fmaf(__bfloat162float(ob[(size_t)(c2 + 3) * M_ * D_]), f3, o3);
  }
  {
    const int c2 = NCH1 - 1;
    const float f = __expf(Ms[c2] - gM);
    T = fmaf(Ls[c2], f, T);
    o0 = fmaf(__bfloat162float(ob[(size_t)c2 * M_ * D_]), f, o0);
  }
  out[(size_t)m * N_ + h * D_ + t] = (o0 + o1 + o2 + o3) / T;
}

// ---------------------------------------------------------------------------
extern "C" void kernel_launch(void* const* d_in, const int* in_sizes, int n_in,
                              void* d_out, int out_size, void* d_ws, size_t ws_size,
                              hipStream_t stream) {
  const float* X  = (const float*)d_in[0];
  const float* Wq = (const float*)d_in[1];
  const float* Wk = (const float*)d_in[2];
  const float* Wv = (const float*)d_in[3];
  const float* cK = (const float*)d_in[4];
  const float* cV = (const float*)d_in[5];
  float* ws    = (float*)d_ws;
  float* qkv   = ws;
  float* part  = ws + PART_OFF;
  __hip_bfloat16* opart = (__hip_bfloat16*)(ws + OPART_OFF);
  float* mlbuf = ws + ML_OFF;
  float* out   = (float*)d_out;

  hipLaunchKernelGGL(k_proj,   dim3(NCB, NIC, 3), dim3(256), 0, stream, X, Wq, Wk, Wv, part);
  hipLaunchKernelGGL(k_reduce, dim3(16, M_, 3),   dim3(256), 0, stream, part, qkv);
  hipLaunchKernelGGL(k_attn,   dim3(NCH1, H_),    dim3(256), 0, stream, cK, cV, qkv, opart, mlbuf);
  hipLaunchKernelGGL(k_comb,   dim3(M_, H_),      dim3(128), 0, stream, opart, mlbuf, out);
}